// Round 12
// baseline (333.319 us; speedup 1.0000x reference)
//
#include <hip/hip_runtime.h>

#define NN 4096   // H*W
#define DD 256    // feature channels
#define CC 19     // classes
#define BB 2      // batch

typedef __attribute__((ext_vector_type(8))) short bf16x8;     // bf16 MFMA A/B frag
typedef _Float16 f16x8 __attribute__((ext_vector_type(8)));   // fp16 MFMA A/B frag
typedef __attribute__((ext_vector_type(4))) float f32x4;      // MFMA C/D frag

#define GLL16(gp, lp) __builtin_amdgcn_global_load_lds( \
    (const __attribute__((address_space(1))) unsigned int*)(gp), \
    (__attribute__((address_space(3))) unsigned int*)(lp), 16, 0, 0)

__device__ inline unsigned short f2b(float f) {   // fp32 -> bf16 RNE
  unsigned int u = __float_as_uint(f);
  return (unsigned short)((u + 0x7FFFu + ((u >> 16) & 1u)) >> 16);
}
__device__ inline float b2f(unsigned short h) {
  return __uint_as_float(((unsigned int)h) << 16);
}
__device__ inline unsigned int pack2(float a, float b) {
  return (unsigned int)f2b(a) | ((unsigned int)f2b(b) << 16);
}
// fp32 -> (fp16 hi, fp16 lo*2^11): hi+2^-11*lo carries ~22 mantissa bits
__device__ inline void split16(float x, unsigned short& h, unsigned short& l) {
  _Float16 hh = (_Float16)x;
  float hf = (float)hh;
  _Float16 ll = (_Float16)((x - hf) * 2048.0f);
  h = *reinterpret_cast<unsigned short*>(&hh);
  l = *reinterpret_cast<unsigned short*>(&ll);
}

// ---------------------------------------------------------------------------
// K1 (merged mask_bits + norm_feat): softmax confidence mask + scrambled
// one-hot bitmasks + row-normalized split-fp16 features.
// ---------------------------------------------------------------------------
__global__ __launch_bounds__(256) void k_prep(const float* __restrict__ pred,
                                              const float* __restrict__ cw,
                                              const float* __restrict__ feat,
                                              float* __restrict__ maskb,
                                              unsigned int* __restrict__ ohbits,
                                              unsigned short* __restrict__ xh,
                                              unsigned short* __restrict__ xl) {
  int g = blockIdx.x * 256 + threadIdx.x;
  int b = g >> 12, n = g & (NN - 1);
  {
    const float* p = pred + (size_t)b * CC * NN + n;
    float v[CC];
    float mx = -1e30f; int am = 0;
#pragma unroll
    for (int c = 0; c < CC; ++c) {
      float t = p[(size_t)c * NN];
      v[c] = t;
      if (t > mx) { mx = t; am = c; }
    }
    float s = 0.f;
#pragma unroll
    for (int c = 0; c < CC; ++c) s += expf(v[c] - mx);
    float pprob = 1.f / s;
    float cmax = 0.f;
#pragma unroll
    for (int c = 0; c < CC; ++c) cmax = fmaxf(cmax, cw[c]);
    float cwm = cw[am] / (cmax + 1e-10f) * 0.95f;
    maskb[g] = (pprob >= 0.95f || pprob >= cwm) ? 1.f : 0.f;
    int h = n >> 6, w = n & 63;
    int L = w * (CC * 64) + am * 64 + h;     // flat index in [W,C,H]
    atomicOr(&ohbits[b * NN + L / CC], 1u << (L % CC));
  }
  {
    const float* f = feat + (size_t)b * DD * NN + n;
    float s = 0.f;
    for (int d = 0; d < DD; ++d) { float t = f[(size_t)d * NN]; s += t * t; }
    float r = 1.f / (sqrtf(s) + 1e-9f);
    size_t ob = ((size_t)b * NN + n) * DD;
    for (int d = 0; d < DD; d += 4) {
      ushort4 oh, ol;
      split16(f[(size_t)d * NN] * r, oh.x, ol.x);
      split16(f[(size_t)(d + 1) * NN] * r, oh.y, ol.y);
      split16(f[(size_t)(d + 2) * NN] * r, oh.z, ol.z);
      split16(f[(size_t)(d + 3) * NN] * r, oh.w, ol.w);
      *reinterpret_cast<ushort4*>(&xh[ob + d]) = oh;
      *reinterpret_cast<ushort4*>(&xl[ob + d]) = ol;
    }
  }
}

// ---------------------------------------------------------------------------
// K3: aff1 = clamp(Gram(xn), 0) via 3-pass split-fp16 MFMA (~fp32 accuracy).
// gll staging, linear LDS, both-sides slot swizzle, dbuf, one barrier per
// K-step.  fp32 output (R7 lesson: quantizing aff1 BEFORE the exact top-21
// selection breaks membership -- keep fp32 until k_symm).
// R25 (T1): XCD-chunked block swizzle -- 528 = 8*66 exactly; XCD k gets
// logical tiles [66k, 66k+66), so each XCD's private L2 sees few distinct
// I-groups and re-uses the i-row X panels (FETCH was 2.2x ideal).
// ---------------------------------------------------------------------------
__global__ __launch_bounds__(256, 2) void k_gram1(const unsigned short* __restrict__ xh,
                                                  const unsigned short* __restrict__ xl,
                                                  float* __restrict__ M) {
  int Lh = blockIdx.x;                 // hardware id 0..527 (round-robin XCDs)
  int L = (Lh & 7) * 66 + (Lh >> 3);   // bijective XCD-contiguous logical tile
  int b = blockIdx.y;
  int I = 0;
  while (L >= 32 - I) { L -= 32 - I; ++I; }
  int J = I + L;
  int i0 = I * 128, j0 = J * 128;
  float* Mb = M + (size_t)b * NN * NN;
  const unsigned short* XH = xh + (size_t)b * NN * DD;
  const unsigned short* XL = xl + (size_t)b * NN * DD;
  __shared__ unsigned short stage[2][4][128][32];   // 64 KB; reused as float buf
  int t = threadIdx.x;
  int wave = t >> 6, lane = t & 63;
  int wr = (wave & 1) * 64, wc = (wave >> 1) * 64;
  int lrow = lane & 15, quad = lane >> 4;
  int sel = (lrow >> 1) & 3;                        // read-side swizzle selector
  f32x4 accH[4][4] = {}, accL[4][4] = {};
  const unsigned short* src = (wave == 0) ? XH + (size_t)i0 * DD
                             : (wave == 1) ? XL + (size_t)i0 * DD
                             : (wave == 2) ? XH + (size_t)j0 * DD
                                           : XL + (size_t)j0 * DD;
  // per-lane staging address components (uniform across e and k0)
  int srow = lane >> 2;                              // row within 16-row group
  int spart = (lane & 3) ^ ((lane >> 3) & 3);        // pre-swizzled global part
  // prologue: stage chunk 0 into buffer 0
#pragma unroll
  for (int e = 0; e < 8; ++e)
    GLL16(&src[(size_t)(e * 16 + srow) * DD + spart * 8], &stage[0][wave][e * 16][0]);
  __syncthreads();
  int cur = 0;
  for (int k0 = 0; k0 < DD; k0 += 32) {
    if (k0 + 32 < DD) {   // async-stage next chunk; retires under the MFMA cluster
#pragma unroll
      for (int e = 0; e < 8; ++e)
        GLL16(&src[(size_t)(e * 16 + srow) * DD + k0 + 32 + spart * 8],
              &stage[cur ^ 1][wave][e * 16][0]);
    }
    f16x8 ah[4], al[4], bh[4], bl[4];
#pragma unroll
    for (int i = 0; i < 4; ++i) {
      int ra = wr + i * 16 + lrow;
      int rb = wc + i * 16 + lrow;
      int sl = (quad ^ sel) * 8;
      ah[i] = *reinterpret_cast<const f16x8*>(&stage[cur][0][ra][sl]);
      al[i] = *reinterpret_cast<const f16x8*>(&stage[cur][1][ra][sl]);
      bh[i] = *reinterpret_cast<const f16x8*>(&stage[cur][2][rb][sl]);
      bl[i] = *reinterpret_cast<const f16x8*>(&stage[cur][3][rb][sl]);
    }
#pragma unroll
    for (int i = 0; i < 4; ++i) {
#pragma unroll
      for (int j = 0; j < 4; ++j) {
        accH[i][j] = __builtin_amdgcn_mfma_f32_16x16x32_f16(ah[i], bh[j], accH[i][j], 0, 0, 0);
        accL[i][j] = __builtin_amdgcn_mfma_f32_16x16x32_f16(ah[i], bl[j], accL[i][j], 0, 0, 0);
        accL[i][j] = __builtin_amdgcn_mfma_f32_16x16x32_f16(al[i], bh[j], accL[i][j], 0, 0, 0);
      }
    }
    __syncthreads();   // drains vmcnt(0)+lgkmcnt(0): next buffer staged, reads done
    cur ^= 1;
  }
#pragma unroll
  for (int i = 0; i < 4; ++i)
#pragma unroll
    for (int j = 0; j < 4; ++j)
#pragma unroll
      for (int reg = 0; reg < 4; ++reg)
        accH[i][j][reg] = fmaxf(accH[i][j][reg] + accL[i][j][reg] * 4.8828125e-4f, 0.f);
  float* buf = (float*)stage;   // [64][132] floats = 33.8 KB <= 64 KB
  int rr = t >> 4, cc = t & 15;
  for (int half = 0; half < 2; ++half) {
    __syncthreads();
    if ((wr >> 6) == half) {
#pragma unroll
      for (int i = 0; i < 4; ++i)
#pragma unroll
        for (int j = 0; j < 4; ++j)
#pragma unroll
          for (int reg = 0; reg < 4; ++reg)
            buf[(i * 16 + quad * 4 + reg) * 132 + wc + j * 16 + lrow] = accH[i][j][reg];
    }
    __syncthreads();
#pragma unroll
    for (int i = 0; i < 4; ++i) {
      int row = rr + i * 16;
#pragma unroll
      for (int q = 0; q < 2; ++q) {
        int col = cc * 4 + q * 64;
        *reinterpret_cast<float4*>(&Mb[(size_t)(i0 + half * 64 + row) * NN + j0 + col]) =
            *reinterpret_cast<float4*>(&buf[row * 132 + col]);
      }
    }
  }
  if (I != J) {
    for (int half = 0; half < 2; ++half) {
      __syncthreads();
      if ((wc >> 6) == half) {
#pragma unroll
        for (int i = 0; i < 4; ++i)
#pragma unroll
          for (int j = 0; j < 4; ++j)
#pragma unroll
            for (int reg = 0; reg < 4; ++reg)
              buf[(j * 16 + lrow) * 132 + wr + i * 16 + quad * 4 + reg] = accH[i][j][reg];
      }
      __syncthreads();
#pragma unroll
      for (int i = 0; i < 4; ++i) {
        int row = rr + i * 16;
#pragma unroll
        for (int q = 0; q < 2; ++q) {
          int col = cc * 4 + q * 64;
          *reinterpret_cast<float4*>(&Mb[(size_t)(j0 + half * 64 + row) * NN + i0 + col]) =
              *reinterpret_cast<float4*>(&buf[row * 132 + col]);
        }
      }
    }
  }
}

// ---------------------------------------------------------------------------
// K4: per-row 21st-largest, ONE WAVE PER ROW, row in VGPRs.
// Pivot-prune select + sched_barrier fences (rule #18) + total
// self-verification with exact full-bisect fallback.
// ---------------------------------------------------------------------------
__global__ __launch_bounds__(256, 2) void k_topk(const float* __restrict__ M,
                                                 float* __restrict__ thr) {
  __shared__ unsigned int cbuf[4][64];
  int b = blockIdx.y;
  int wave = threadIdx.x >> 6, lane = threadIdx.x & 63;
  int n = blockIdx.x * 4 + wave;
  const float* row = M + (size_t)b * NN * NN + (size_t)n * NN;
  uint4 v[16];
#pragma unroll
  for (int e = 0; e < 16; ++e) {
    unsigned long long addr = (unsigned long long)(row + lane * 4 + e * 256);
    asm volatile("global_load_dwordx4 %0, %1, off" : "=v"(v[e]) : "v"(addr));
  }
  asm volatile("s_waitcnt vmcnt(0)" ::: "memory");
  __builtin_amdgcn_sched_barrier(0);   // rule #18: pin register-only consumers below the wait
  // ---- phase 1: per-lane max ----
  unsigned int mx = 0u;
#pragma unroll
  for (int e = 0; e < 16; ++e) {
    unsigned int a = v[e].x > v[e].y ? v[e].x : v[e].y;
    unsigned int c2 = v[e].z > v[e].w ? v[e].z : v[e].w;
    a = a > c2 ? a : c2;
    mx = mx > a ? mx : a;
  }
  // ---- phase 2: s = 21st-largest lane-max (1 value per lane) ----
  unsigned int lo = 0u, hi = 0x3FC00000u;   // values in [0, ~1.001]; 1.5f bound
  while (lo < hi) {
    unsigned int mid = lo + ((hi - lo + 1) >> 1);
    if (__popcll(__ballot(mx >= mid)) >= 21) lo = mid; else hi = mid - 1;
  }
  unsigned int s = lo;
  // ---- phase 3: compact values >= s into LDS ----
  unsigned int base = 0;
  unsigned long long ltmask = (1ull << lane) - 1ull;
#pragma unroll
  for (int e = 0; e < 16; ++e) {
#pragma unroll
    for (int q = 0; q < 4; ++q) {
      unsigned int val = (q == 0) ? v[e].x : (q == 1) ? v[e].y : (q == 2) ? v[e].z : v[e].w;
      unsigned long long mk = __ballot(val >= s);
      if (mk) {   // wave-uniform skip: most elements are below the pivot
        unsigned int pos = base + (unsigned int)__popcll(mk & ltmask);
        if (val >= s && pos < 64u) cbuf[wave][pos] = val;
        base += (unsigned int)__popcll(mk);
      }
    }
  }
  asm volatile("s_waitcnt lgkmcnt(0)" ::: "memory");
  __builtin_amdgcn_sched_barrier(0);
  unsigned int t = s;
  if (base <= 64u) {
    // ---- phase 4: exact bisect over <=64 compacted candidates ----
    unsigned int cand = (lane < (int)base) ? cbuf[wave][lane] : 0u;
    lo = s; hi = 0x3FC00000u;
    while (lo < hi) {
      unsigned int mid = lo + ((hi - lo + 1) >> 1);
      if (__popcll(__ballot(cand >= mid)) >= 21) lo = mid; else hi = mid - 1;
    }
    t = lo;
  }
  // ---- phase 5: total verification (t exact iff c1>=21 && c2<21) ----
  {
    unsigned int t1 = t + 1u;
    int c1 = 0, c2 = 0;
#pragma unroll
    for (int e = 0; e < 16; ++e) {
      c1 += (int)__popcll(__ballot(v[e].x >= t));
      c1 += (int)__popcll(__ballot(v[e].y >= t));
      c1 += (int)__popcll(__ballot(v[e].z >= t));
      c1 += (int)__popcll(__ballot(v[e].w >= t));
      c2 += (int)__popcll(__ballot(v[e].x >= t1));
      c2 += (int)__popcll(__ballot(v[e].y >= t1));
      c2 += (int)__popcll(__ballot(v[e].z >= t1));
      c2 += (int)__popcll(__ballot(v[e].w >= t1));
    }
    if (!(c1 >= 21 && c2 < 21)) {
      // exact fallback: original proven full-sweep bisection
      lo = 0u; hi = 0x40000000u;
      while (lo < hi) {
        unsigned int mid = lo + ((hi - lo + 1) >> 1);
        int c = 0;
#pragma unroll
        for (int e = 0; e < 16; ++e) {
          c += (int)__popcll(__ballot(v[e].x >= mid));
          c += (int)__popcll(__ballot(v[e].y >= mid));
          c += (int)__popcll(__ballot(v[e].z >= mid));
          c += (int)__popcll(__ballot(v[e].w >= mid));
        }
        if (c >= 21) lo = mid; else hi = mid - 1;
      }
      t = lo;
    }
  }
  if (lane == 0) thr[b * NN + n] = __uint_as_float(t);
}

// ---------------------------------------------------------------------------
// K5: sparsify + symmetrize.  aff1 is bit-exact symmetric, so
// As[i][j] = a*(1(a>=thr_i) + 1(a>=thr_j)) needs ONLY the (I,J) tile.
// Writes bf16 As packed into each tile's fp32 footprint + degree sums.
// ---------------------------------------------------------------------------
__global__ __launch_bounds__(256) void k_symm(float* __restrict__ M, const float* __restrict__ thr,
                                              float* __restrict__ dsum) {
  int L = blockIdx.x;          // 0..2079 triangular (64 tiles/dim)
  int b = blockIdx.y;
  int I = 0;
  while (L >= 64 - I) { L -= 64 - I; ++I; }
  int J = I + L;
  float* Mb = M + (size_t)b * NN * NN;
  unsigned short* Mus = (unsigned short*)Mb;
  const float* th = thr + b * NN;
  __shared__ float A[64][65];
  int t = threadIdx.x;
  int i0 = I * 64, j0 = J * 64;
  float areg[16];
#pragma unroll
  for (int e = 0; e < 16; ++e) {
    int lin = t + e * 256;
    int i = lin >> 6, j = lin & 63;
    areg[e] = Mb[(size_t)(i0 + i) * NN + j0 + j];
  }
#pragma unroll
  for (int e = 0; e < 16; ++e) {
    int lin = t + e * 256;
    int i = lin >> 6, j = lin & 63;
    float a = areg[e];
    float v = a * ((a >= th[i0 + i] ? 1.f : 0.f) + (a >= th[j0 + j] ? 1.f : 0.f));
    A[i][j] = v;
  }
  __syncthreads();
  {
    int i = t >> 2, seg = (t & 3) * 16;
    float v[16];
#pragma unroll
    for (int q = 0; q < 4; ++q)
      *reinterpret_cast<float4*>(&v[q * 4]) = *reinterpret_cast<float4*>(&A[i][seg + q * 4]);
    unsigned int pk[8];
#pragma unroll
    for (int q = 0; q < 8; ++q) pk[q] = pack2(v[2 * q], v[2 * q + 1]);
    size_t ub = 2 * (size_t)(i0 + i) * NN + 2 * (size_t)j0 + seg;
    *reinterpret_cast<int4*>(&Mus[ub])     = *reinterpret_cast<int4*>(&pk[0]);
    *reinterpret_cast<int4*>(&Mus[ub + 8]) = *reinterpret_cast<int4*>(&pk[4]);
  }
  if (I != J) {   // As is symmetric: mirror footprint gets A^T
    int j = t >> 2, seg = (t & 3) * 16;
    float v[16];
#pragma unroll
    for (int e = 0; e < 16; ++e) v[e] = A[seg + e][j];
    unsigned int pk[8];
#pragma unroll
    for (int q = 0; q < 8; ++q) pk[q] = pack2(v[2 * q], v[2 * q + 1]);
    size_t ub = 2 * (size_t)(j0 + j) * NN + 2 * (size_t)i0 + seg;
    *reinterpret_cast<int4*>(&Mus[ub])     = *reinterpret_cast<int4*>(&pk[0]);
    *reinterpret_cast<int4*>(&Mus[ub + 8]) = *reinterpret_cast<int4*>(&pk[4]);
  }
  if (t < 64) {
    float s = 0.f;
#pragma unroll
    for (int j = 0; j < 64; ++j) s += A[t][j];
    atomicAdd(&dsum[b * NN + i0 + t], s);
  } else if (t < 128 && I != J) {
    int j = t - 64;
    float s = 0.f;
#pragma unroll
    for (int i = 0; i < 64; ++i) s += A[i][j];
    atomicAdd(&dsum[b * NN + j0 + j], s);
  }
}

// ---------------------------------------------------------------------------
// K7: ybh[b][c][n] = bf16(d1[b][n] * pred[b][c][n]), zero-padded to 32 classes.
// d1 is the RAW degree sum; 1/sqrt(d+1e-10) inlined.
// ---------------------------------------------------------------------------
__global__ void k_make_yb(const float* __restrict__ pred, const float* __restrict__ d1,
                          unsigned short* __restrict__ ybh) {
  int g = blockIdx.x * 256 + threadIdx.x;   // BB*32*NN/4 threads
  int idx = g * 4;
  int b = idx / (32 * NN);
  int c = (idx / NN) & 31;
  int n = idx & (NN - 1);
  ushort4 o = make_ushort4(0, 0, 0, 0);
  if (c < CC) {
    float4 p = *reinterpret_cast<const float4*>(&pred[((size_t)b * CC + c) * NN + n]);
    const float* dd = d1 + b * NN + n;
    o.x = f2b(p.x * (1.f / sqrtf(dd[0] + 1e-10f)));
    o.y = f2b(p.y * (1.f / sqrtf(dd[1] + 1e-10f)));
    o.z = f2b(p.z * (1.f / sqrtf(dd[2] + 1e-10f)));
    o.w = f2b(p.w * (1.f / sqrtf(dd[3] + 1e-10f)));
  }
  *reinterpret_cast<ushort4*>(&ybh[idx]) = o;
}

// ---------------------------------------------------------------------------
// K8: p2 via MFMA.  GEMM: M=n (64-tile), N=c (32 padded), K=m (4096).
// gll staging, both-sides slot-XOR swizzle, dbuf, one barrier per K-step.
// d1 raw; rsqrt inlined in the epilogue.
// ---------------------------------------------------------------------------
__global__ __launch_bounds__(256, 2) void k_p2_mfma(
    const float* __restrict__ M, const unsigned short* __restrict__ ybh,
    const float* __restrict__ d1, float* __restrict__ p2b) {
  int b = blockIdx.y;
  int n0 = blockIdx.x * 64;
  const unsigned short* Mus = (const unsigned short*)(M + (size_t)b * NN * NN);
  const unsigned short* Y = ybh + (size_t)b * 32 * NN;
  __shared__ unsigned short As2[2][64][64];   // 16 KB
  __shared__ unsigned short Ys2[2][32][64];   // 8 KB
  int t = threadIdx.x;
  int wave = t >> 6, lane = t & 63;
  int wn = (wave & 1) * 32;
  int wc = (wave >> 1) * 16;
  int lrow = lane & 15, quad = lane >> 4;
  f32x4 acc[2] = {{0.f,0.f,0.f,0.f},{0.f,0.f,0.f,0.f}};
  // staging geometry: each GLL16 issue covers 8 rows x 128 B
  int lr3 = lane >> 3;                   // row within the 8-row group
  int srow = wave * 8 + lr3;             // + e*32 for As; direct for Ys
  int spart = (lane & 7) ^ lr3;          // pre-swizzled global 16B-part
  // prologue: stage K-chunk 0 into buffer 0
#pragma unroll
  for (int e = 0; e < 2; ++e)
    GLL16(&Mus[2 * (size_t)(n0 + e * 32 + srow) * NN + spart * 8],
          &As2[0][e * 32 + wave * 8][0]);
  GLL16(&Y[(size_t)srow * NN + spart * 8], &Ys2[0][wave * 8][0]);
  __syncthreads();
  int cur = 0;
  for (int m0 = 0; m0 < NN; m0 += 64) {
    if (m0 + 64 < NN) {   // async-stage next chunk; retires under the MFMA cluster
#pragma unroll
      for (int e = 0; e < 2; ++e)
        GLL16(&Mus[2 * (size_t)(n0 + e * 32 + srow) * NN + 2 * (size_t)(m0 + 64) + spart * 8],
              &As2[cur ^ 1][e * 32 + wave * 8][0]);
      GLL16(&Y[(size_t)srow * NN + m0 + 64 + spart * 8], &Ys2[cur ^ 1][wave * 8][0]);
    }
#pragma unroll
    for (int kc = 0; kc < 2; ++kc) {
      int sl = ((kc * 4 + quad) ^ (lrow & 7)) * 8;   // swizzled slot (shorts)
      bf16x8 bfr = *reinterpret_cast<const bf16x8*>(&Ys2[cur][wc + lrow][sl]);
#pragma unroll
      for (int i = 0; i < 2; ++i) {
        bf16x8 af = *reinterpret_cast<const bf16x8*>(&As2[cur][wn + i * 16 + lrow][sl]);
        acc[i] = __builtin_amdgcn_mfma_f32_16x16x32_bf16(af, bfr, acc[i], 0, 0, 0);
      }
    }
    __syncthreads();   // drains vmcnt(0)+lgkmcnt(0): next buffer staged, reads done
    cur ^= 1;
  }
  int c = wc + lrow;
  if (c < CC) {
#pragma unroll
    for (int i = 0; i < 2; ++i) {
#pragma unroll
      for (int reg = 0; reg < 4; ++reg) {
        int n = n0 + wn + i * 16 + quad * 4 + reg;
        float dv = 1.f / sqrtf(d1[b * NN + n] + 1e-10f);
        p2b[((size_t)b * NN + n) * CC + c] = dv * acc[i][reg];
      }
    }
  }
}

// ---------------------------------------------------------------------------
// K9: fused blend + 19x19 conv x2 -> pred_out, then softmax + cosine-normalize.
// Emits spnP[b][n][32] bf16 (zero-padded K) for the MFMA k_gram2.
// ---------------------------------------------------------------------------
__global__ __launch_bounds__(256) void k_pred_head(const float* __restrict__ pred,
    const float* __restrict__ p2b, const float* __restrict__ maskb,
    const float* __restrict__ w1, const float* __restrict__ b1,
    const float* __restrict__ w2, const float* __restrict__ b2,
    float* __restrict__ out, unsigned short* __restrict__ spnP) {
  __shared__ float sw1[CC * CC], sw2[CC * CC], sb1[CC], sb2[CC];
  int t = threadIdx.x;
  for (int i = t; i < CC * CC; i += 256) { sw1[i] = w1[i]; sw2[i] = w2[i]; }
  if (t < CC) { sb1[t] = b1[t]; sb2[t] = b2[t]; }
  __syncthreads();
  int g = blockIdx.x * 256 + t;
  int b = g >> 12, n = g & (NN - 1);
  float m = maskb[g];
  float ca = (m > 0.5f) ? 0.2f : 0.8f;
  float cb = (m > 0.5f) ? 0.8f : 0.2f;
  const float* P = pred + (size_t)b * CC * NN + n;
  const float* Q = p2b + (size_t)g * CC;
  float p3[CC];
#pragma unroll
  for (int c = 0; c < CC; ++c) p3[c] = ca * Q[c] + cb * P[(size_t)c * NN];
  float midv[CC];
#pragma unroll
  for (int o = 0; o < CC; ++o) {
    float s = sb1[o];
#pragma unroll
    for (int c = 0; c < CC; ++c) s += sw1[o * CC + c] * p3[c];
    midv[o] = s;
  }
  float ov[CC];
  float mx = -1e30f;
#pragma unroll
  for (int o = 0; o < CC; ++o) {
    float s = sb2[o];
#pragma unroll
    for (int c = 0; c < CC; ++c) s += sw2[o * CC + c] * midv[c];
    ov[o] = s;
    out[(size_t)b * CC * NN + (size_t)o * NN + n] = s;
    mx = fmaxf(mx, s);
  }
  float se = 0.f;
  float e[CC];
#pragma unroll
  for (int o = 0; o < CC; ++o) { e[o] = expf(ov[o] - mx); se += e[o]; }
  float inv = 1.f / se;
  float nrm = 0.f;
#pragma unroll
  for (int o = 0; o < CC; ++o) { float sp = e[o] * inv; e[o] = sp; nrm += sp * sp; }
  float rn = 1.f / (sqrtf(nrm) + 1e-9f);
  unsigned short sp[32];
#pragma unroll
  for (int o = 0; o < CC; ++o) sp[o] = f2b(e[o] * rn);
#pragma unroll
  for (int o = CC; o < 32; ++o) sp[o] = 0;
  unsigned short* dst = spnP + (size_t)g * 32;
#pragma unroll
  for (int q = 0; q < 4; ++q)
    *reinterpret_cast<int4*>(&dst[q * 8]) = *reinterpret_cast<int4*>(&sp[q * 8]);
}

// ---------------------------------------------------------------------------
// K10: aff_f = bitmask ? clamp(Gram(spn),0) : 0, writes bf16 + fused d2 sums.
// MFMA (16x16x32, K padded to 32); gll staging with the verified slot
// swizzle; epilogue via tr[64][66] ushort (conflict-free columns).
// Safe in bf16: NO selection operates downstream of aff_f.
// ---------------------------------------------------------------------------
__global__ __launch_bounds__(256) void k_gram2(const unsigned short* __restrict__ spnP,
    const unsigned int* __restrict__ bits, unsigned short* __restrict__ Mh,
    float* __restrict__ d2) {
  int L = blockIdx.x;          // 0..2079 triangular (64 tiles/dim)
  int b = blockIdx.y;
  int I = 0;
  while (L >= 64 - I) { L -= 64 - I; ++I; }
  int J = I + L;
  const unsigned short* X = spnP + (size_t)b * NN * 32;
  unsigned short* Mb = Mh + (size_t)b * NN * NN;
  __shared__ unsigned short As[64][32], Bs[64][32];   // 4 KB each
  __shared__ unsigned short tr[64][66];               // 8.25 KB
  __shared__ unsigned int bI[64], bJ[64];
  int t = threadIdx.x;
  int wave = t >> 6, lane = t & 63;
  int lrow = lane & 15, quad = lane >> 4;
  int i0 = I * 64, j0 = J * 64;
  // stage: each wave covers 16 rows (lane>>2) x 4 parts (lane&3), swizzled
  int srow = wave * 16 + (lane >> 2);
  int spart = (lane & 3) ^ ((lane >> 3) & 3);
  GLL16(&X[(size_t)(i0 + srow) * 32 + spart * 8], &As[wave * 16][0]);
  GLL16(&X[(size_t)(j0 + srow) * 32 + spart * 8], &Bs[wave * 16][0]);
  if (t < 64) bI[t] = bits[b * NN + i0 + t];
  else if (t < 128) bJ[t - 64] = bits[b * NN + j0 + t - 64];
  __syncthreads();
  int wi = wave & 1, wj = wave >> 1;
  int sl = (quad ^ ((lrow >> 1) & 3)) * 8;   // read-side swizzle (matches k_gram1)
  bf16x8 af[2], bfr[2];
#pragma unroll
  for (int i = 0; i < 2; ++i) {
    af[i]  = *reinterpret_cast<const bf16x8*>(&As[wi * 32 + i * 16 + lrow][sl]);
    bfr[i] = *reinterpret_cast<const bf16x8*>(&Bs[wj * 32 + i * 16 + lrow][sl]);
  }
  f32x4 acc[2][2] = {{{0.f,0.f,0.f,0.f},{0.f,0.f,0.f,0.f}},{{0.f,0.f,0.f,0.f},{0.f,0.f,0.f,0.f}}};
#pragma unroll
  for (int i = 0; i < 2; ++i)
#pragma unroll
    for (int j = 0; j < 2; ++j)
      acc[i][j] = __builtin_amdgcn_mfma_f32_16x16x32_bf16(af[i], bfr[j], acc[i][j], 0, 0, 0);
  // mask + clamp + round -> tr
#pragma unroll
  for (int i = 0; i < 2; ++i) {
#pragma unroll
    for (int j = 0; j < 2; ++j) {
#pragma unroll
      for (int reg = 0; reg < 4; ++reg) {
        int row = wi * 32 + i * 16 + quad * 4 + reg;
        int col = wj * 32 + j * 16 + lrow;
        bool keep = (bI[row] & bJ[col]) != 0u;
        float v = keep ? fmaxf(acc[i][j][reg], 0.f) : 0.f;
        tr[row][col] = f2b(v);
      }
    }
  }
  __syncthreads();
  // direct tile store (coalesced; 4B LDS reads, 2-way max aliasing)
  {
    int row = t >> 2, seg = (t & 3) * 16;
    unsigned int w[8];
#pragma unroll
    for (int k = 0; k < 8; ++k)
      w[k] = *reinterpret_cast<const unsigned int*>(&tr[row][seg + 2 * k]);
    *reinterpret_cast<int4*>(&Mb[(size_t)(i0 + row) * NN + j0 + seg])     =
        *reinterpret_cast<int4*>(&w[0]);
    *reinterpret_cast<int4*>(&Mb[(size_t)(i0 + row) * NN + j0 + seg + 8]) =
        *reinterpret_cast<int4*>(&w[4]);
  }
  if (I != J) {   // mirror transposed store (conflict-free column reads)
#pragma unroll
    for (int e = 0; e < 16; ++e) {
      int lin = t + e * 256;
      int jr = lin >> 6, ic = lin & 63;
      Mb[(size_t)(j0 + jr) * NN + i0 + ic] = tr[ic][jr];
    }
  }
  if (t < 64) {          // direct row sums
    float s = 0.f;
#pragma unroll
    for (int c = 0; c < 64; ++c) s += b2f(tr[t][c]);
    atomicAdd(&d2[b * NN + i0 + t], s);
  } else if (t < 128 && I != J) {   // mirror row sums (column of tr)
    int c = t - 64;
    float s = 0.f;
#pragma unroll
    for (int i = 0; i < 64; ++i) s += b2f(tr[i][c]);
    atomicAdd(&d2[b * NN + j0 + c], s);
  }
}

// ---------------------------------------------------------------------------
// K12a: zb[b][d][m] = bf16(feat[b][d][m] * d2[b][m]); d2 raw, rsqrt inline
// ---------------------------------------------------------------------------
__global__ void k_make_z(const float* __restrict__ feat, const float* __restrict__ d2,
                         unsigned short* __restrict__ zb) {
  int g = blockIdx.x * 256 + threadIdx.x;   // BB*DD*NN/4 threads
  int idx = g * 4;
  int b = idx / (DD * NN);
  int m = idx & (NN - 1);
  float4 f = *reinterpret_cast<const float4*>(&feat[idx]);
  const float* dd = d2 + b * NN + m;
  ushort4 o;
  o.x = f2b(f.x * (1.f / sqrtf(dd[0] + 1e-10f)));
  o.y = f2b(f.y * (1.f / sqrtf(dd[1] + 1e-10f)));
  o.z = f2b(f.z * (1.f / sqrtf(dd[2] + 1e-10f)));
  o.w = f2b(f.w * (1.f / sqrtf(dd[3] + 1e-10f)));
  *reinterpret_cast<ushort4*>(&zb[idx]) = o;
}

// K12b: convert projection weights to bf16
__global__ void k_prep_w(const float* __restrict__ w1, const float* __restrict__ w2,
                         unsigned short* __restrict__ wb1, unsigned short* __restrict__ wb2) {
  int g = blockIdx.x * 256 + threadIdx.x;   // DD*DD threads
  wb1[g] = f2b(w1[g]);
  wb2[g] = f2b(w2[g]);
}

// ---------------------------------------------------------------------------
// K13: new_feat via MFMA.  GEMM: M=d(64), N=n(64), K=4096.
// Single kernel accumulates full K, epilogue applies rsqrt(d2) and stores
// bf16 nfh directly.  gll/dbuf/swizzle K-step structure.
// ---------------------------------------------------------------------------
__global__ __launch_bounds__(256, 2) void k_newfeat_mfma(
    const unsigned short* __restrict__ Mh, const unsigned short* __restrict__ zb,
    const float* __restrict__ d2, unsigned short* __restrict__ nfh) {
  int b = blockIdx.z;
  int nblk = blockIdx.x;   // 64
  int dblk = blockIdx.y;   // 4
  const unsigned short* A = zb + (size_t)b * DD * NN + (size_t)(dblk * 64) * NN;
  const unsigned short* Bm = Mh + (size_t)b * NN * NN + (size_t)(nblk * 64) * NN;
  __shared__ unsigned short As[2][64][64];   // 16 KB
  __shared__ unsigned short Bs[2][64][64];   // 16 KB
  int t = threadIdx.x;
  int wave = t >> 6, lane = t & 63;
  int wd = (wave & 1) * 32, wn = (wave >> 1) * 32;
  int lrow = lane & 15, quad = lane >> 4;
  f32x4 acc[2][2] = {{{0.f,0.f,0.f,0.f},{0.f,0.f,0.f,0.f}},{{0.f,0.f,0.f,0.f},{0.f,0.f,0.f,0.f}}};
  // staging geometry: per wave, issue e covers rows e*32 + wave*8 .. +8
  int lr3 = lane >> 3;                   // 0..7: row within the wave's 8-row group
  int srow = wave * 8 + lr3;             // + e*32 = global tile row
  int spart = (lane & 7) ^ lr3;          // pre-swizzled global 16B-part
  // prologue: stage K-chunk 0 into buffer 0
#pragma unroll
  for (int e = 0; e < 2; ++e) {
    GLL16(&A [(size_t)(e * 32 + srow) * NN + spart * 8], &As[0][e * 32 + wave * 8][0]);
    GLL16(&Bm[(size_t)(e * 32 + srow) * NN + spart * 8], &Bs[0][e * 32 + wave * 8][0]);
  }
  __syncthreads();
  int cur = 0;
  for (int m0 = 0; m0 < NN; m0 += 64) {
    if (m0 + 64 < NN) {   // async-stage next chunk; retires under the MFMA cluster
#pragma unroll
      for (int e = 0; e < 2; ++e) {
        GLL16(&A [(size_t)(e * 32 + srow) * NN + m0 + 64 + spart * 8],
              &As[cur ^ 1][e * 32 + wave * 8][0]);
        GLL16(&Bm[(size_t)(e * 32 + srow) * NN + m0 + 64 + spart * 8],
              &Bs[cur ^ 1][e * 32 + wave * 8][0]);
      }
    }
#pragma unroll
    for (int kc = 0; kc < 2; ++kc) {
      int sl = ((kc * 4 + quad) ^ (lrow & 7)) * 8;   // swizzled slot (shorts)
      bf16x8 af[2], bfr[2];
#pragma unroll
      for (int i = 0; i < 2; ++i) {
        af[i]  = *reinterpret_cast<const bf16x8*>(&As[cur][wd + i * 16 + lrow][sl]);
        bfr[i] = *reinterpret_cast<const bf16x8*>(&Bs[cur][wn + i * 16 + lrow][sl]);
      }
#pragma unroll
      for (int i = 0; i < 2; ++i)
#pragma unroll
        for (int j = 0; j < 2; ++j)
          acc[i][j] = __builtin_amdgcn_mfma_f32_16x16x32_bf16(af[i], bfr[j], acc[i][j], 0, 0, 0);
    }
    __syncthreads();   // drains vmcnt(0)+lgkmcnt(0): next buffer staged, reads done
    cur ^= 1;
  }
#pragma unroll
  for (int j = 0; j < 2; ++j) {
    int n = nblk * 64 + wn + j * 16 + lrow;
    float sc = 1.f / sqrtf(d2[b * NN + n] + 1e-10f);
#pragma unroll
    for (int i = 0; i < 2; ++i) {
      int d = dblk * 64 + wd + i * 16 + quad * 4;
      ushort4 o;
      o.x = f2b(acc[i][j].x * sc); o.y = f2b(acc[i][j].y * sc);
      o.z = f2b(acc[i][j].z * sc); o.w = f2b(acc[i][j].w * sc);
      *reinterpret_cast<ushort4*>(&nfh[((size_t)b * NN + n) * DD + d]) = o;
    }
  }
}

// ---------------------------------------------------------------------------
// K14: conv1 via MFMA. GEMM: M=n, N=o1, K=d.
// ---------------------------------------------------------------------------
__global__ __launch_bounds__(256) void k_conv1_mfma(
    const unsigned short* __restrict__ nfh, const unsigned short* __restrict__ wb1,
    const float* __restrict__ b1, unsigned short* __restrict__ midh) {
  int b = blockIdx.z;
  int nblk = blockIdx.x;   // 64
  int oblk = blockIdx.y;   // 4
  int n0 = nblk * 64, o0 = oblk * 64;
  __shared__ unsigned short As[64][72];
  __shared__ unsigned short Bs[64][72];
  int t = threadIdx.x;
  int wave = t >> 6, lane = t & 63;
  int wn = (wave & 1) * 32, wo = (wave >> 1) * 32;
  int lrow = lane & 15, quad = lane >> 4;
  f32x4 acc[2][2] = {{{0.f,0.f,0.f,0.f},{0.f,0.f,0.f,0.f}},{{0.f,0.f,0.f,0.f},{0.f,0.f,0.f,0.f}}};
  int sr = t >> 3, sc = (t & 7) * 8;
  for (int d0 = 0; d0 < DD; d0 += 64) {
#pragma unroll
    for (int e = 0; e < 2; ++e) {
      int rr = sr + e * 32;
      *reinterpret_cast<int4*>(&As[rr][sc]) =
          *reinterpret_cast<const int4*>(&nfh[((size_t)b * NN + n0 + rr) * DD + d0 + sc]);
      *reinterpret_cast<int4*>(&Bs[rr][sc]) =
          *reinterpret_cast<const int4*>(&wb1[(size_t)(o0 + rr) * DD + d0 + sc]);
    }
    __syncthreads();
#pragma unroll
    for (int kc = 0; kc < 2; ++kc) {
      int ko = kc * 32 + quad * 8;
      bf16x8 af[2], bfr[2];
#pragma unroll
      for (int i = 0; i < 2; ++i) {
        af[i]  = *reinterpret_cast<const bf16x8*>(&As[wn + i * 16 + lrow][ko]);
        bfr[i] = *reinterpret_cast<const bf16x8*>(&Bs[wo + i * 16 + lrow][ko]);
      }
#pragma unroll
      for (int i = 0; i < 2; ++i)
#pragma unroll
        for (int j = 0; j < 2; ++j)
          acc[i][j] = __builtin_amdgcn_mfma_f32_16x16x32_bf16(af[i], bfr[j], acc[i][j], 0, 0, 0);
    }
    __syncthreads();
  }
#pragma unroll
  for (int j = 0; j < 2; ++j) {
    int o = o0 + wo + j * 16 + lrow;
    float bias = b1[o];
#pragma unroll
    for (int i = 0; i < 2; ++i) {
      int nb = n0 + wn + i * 16 + quad * 4;
      ushort4 v;
      v.x = f2b(fmaxf(acc[i][j].x + bias, 0.f));
      v.y = f2b(fmaxf(acc[i][j].y + bias, 0.f));
      v.z = f2b(fmaxf(acc[i][j].z + bias, 0.f));
      v.w = f2b(fmaxf(acc[i][j].w + bias, 0.f));
      *reinterpret_cast<ushort4*>(&midh[((size_t)b * DD + o) * NN + nb]) = v;
    }
  }
}

// ---------------------------------------------------------------------------
// K15: conv2 via MFMA. GEMM: M=n, N=o2, K=o1.
// ---------------------------------------------------------------------------
__global__ __launch_bounds__(256) void k_conv2_mfma(
    const unsigned short* __restrict__ midh, const unsigned short* __restrict__ wb2,
    const float* __restrict__ b2, float* __restrict__ outp) {
  int b = blockIdx.z;
  int nblk = blockIdx.x;   // 64
  int oblk = blockIdx.y;   // 4
  int n0 = nblk * 64, o0 = oblk * 64;
  __shared__ unsigned short As[64][72];
  __shared__ unsigned short Bs[64][72];
  int t = threadIdx.x;
  int wave = t >> 6, lane = t & 63;
  int wn = (wave & 1) * 32, wo = (wave >> 1) * 32;
  int lrow = lane & 15, quad = lane >> 4;
  f32x4 acc[2][2] = {{{0.f,0.f,0.f,0.f},{0.f,0.f,0.f,0.f}},{{0.f,0.f,0.f,0.f},{0.f,0.f,0.f,0.f}}};
  int sr = t >> 3, sc = (t & 7) * 8;
  for (int d0 = 0; d0 < DD; d0 += 64) {
#pragma unroll
    for (int e = 0; e < 2; ++e) {
      int rr = sr + e * 32;
      *reinterpret_cast<int4*>(&Bs[rr][sc]) =
          *reinterpret_cast<const int4*>(&wb2[(size_t)(o0 + rr) * DD + d0 + sc]);
      unsigned short v[8];
      *reinterpret_cast<int4*>(v) =
          *reinterpret_cast<const int4*>(&midh[((size_t)b * DD + d0 + rr) * NN + n0 + sc]);
#pragma unroll
      for (int j = 0; j < 8; ++j) As[sc + j][rr] = v[j];
    }
    __syncthreads();
#pragma unroll
    for (int kc = 0; kc < 2; ++kc) {
      int ko = kc * 32 + quad * 8;
      bf16x8 af[2], bfr[2];
#pragma unroll
      for (int i = 0; i < 2; ++i) {
        af[i]  = *reinterpret_cast<const bf16x8*>(&As[wn + i * 16 + lrow][ko]);
        bfr[i] = *reinterpret_cast<const bf16x8*>(&Bs[wo + i * 16 + lrow][ko]);
      }
#pragma unroll
      for (int i = 0; i < 2; ++i)
#pragma unroll
        for (int j = 0; j < 2; ++j)
          acc[i][j] = __builtin_amdgcn_mfma_f32_16x16x32_bf16(af[i], bfr[j], acc[i][j], 0, 0, 0);
    }
    __syncthreads();
  }
#pragma unroll
  for (int j = 0; j < 2; ++j) {
    int o = o0 + wo + j * 16 + lrow;
    float bias = b2[o];
#pragma unroll
    for (int i = 0; i < 2; ++i) {
      int nb = n0 + wn + i * 16 + quad * 4;
      float4 v = make_float4(acc[i][j].x + bias, acc[i][j].y + bias,
                             acc[i][j].z + bias, acc[i][j].w + bias);
      *reinterpret_cast<float4*>(&outp[((size_t)b * DD + o) * NN + nb]) = v;
    }
  }
}

// ---------------------------------------------------------------------------
extern "C" void kernel_launch(void* const* d_in, const int* in_sizes, int n_in,
                              void* d_out, int out_size, void* d_ws, size_t ws_size,
                              hipStream_t stream) {
  (void)in_sizes; (void)n_in; (void)out_size; (void)ws_size;
  const float* pred   = (const float*)d_in[0];
  const float* feat   = (const float*)d_in[1];
  const float* w_cls1 = (const float*)d_in[2];
  const float* b_cls1 = (const float*)d_in[3];
  const float* w_cls2 = (const float*)d_in[4];
  const float* b_cls2 = (const float*)d_in[5];
  const float* w_pro1 = (const float*)d_in[6];
  const float* b_pro1 = (const float*)d_in[7];
  const float* w_pro2 = (const float*)d_in[8];
  const float* b_pro2 = (const float*)d_in[9];
  const float* cw     = (const float*)d_in[10];
  float* out = (float*)d_out;

  // workspace layout
  float* Mbuf = (float*)d_ws;                               // B*N*N fp32 (aff1 / packed-bf16 As / bf16 aff_f)
  float* spnT = Mbuf + (size_t)BB * NN * NN;                 // region reused: spnP bf16 [B][N][32]
  float* p2b  = spnT + (size_t)BB * CC * NN;
  float* thr  = p2b + (size_t)BB * NN * CC;
  float* dsum = thr + BB * NN;                               // raw d1 sums
  float* d2s  = dsum + BB * NN;                              // raw d2 sums (contiguous with dsum)
  float* maskb = d2s + BB * NN;
  unsigned int* ohbits = (unsigned int*)(maskb + BB * NN);
  unsigned short* xh   = (unsigned short*)(ohbits + BB * NN);  // B*N*D fp16 hi
  unsigned short* xl   = xh + (size_t)BB * NN * DD;            // B*N*D fp16 lo*2^11
  unsigned short* nfh  = xl + (size_t)BB * NN * DD;            // B*N*D bf16
  unsigned short* midh = nfh + (size_t)BB * NN * DD;           // B*D*N bf16
  unsigned short* zb   = midh + (size_t)BB * DD * NN;          // B*D*N bf16
  unsigned short* wb1  = zb + (size_t)BB * DD * NN;            // D*D bf16
  unsigned short* wb2  = wb1 + (size_t)DD * DD;                // D*D bf16
  unsigned short* ybh  = wb2 + (size_t)DD * DD;                // B*32*N bf16 (padded y)
  unsigned short* Mh   = (unsigned short*)Mbuf;
  unsigned short* spnP = (unsigned short*)spnT;                // bf16 [B][N][32]

  hipMemsetAsync(dsum, 0, sizeof(float) * 2 * BB * NN, stream);   // dsum + d2s
  hipMemsetAsync(ohbits, 0, sizeof(unsigned int) * BB * NN, stream);

  // --- pred branch ---
  k_prep<<<BB * NN / 256, 256, 0, stream>>>(pred, cw, feat, maskb, ohbits, xh, xl);
  k_gram1<<<dim3(528, BB), 256, 0, stream>>>(xh, xl, Mbuf);
  k_topk<<<dim3(NN / 4, BB), 256, 0, stream>>>(Mbuf, thr);
  k_symm<<<dim3(2080, BB), 256, 0, stream>>>(Mbuf, thr, dsum);
  k_make_yb<<<BB * 32 * NN / 4 / 256, 256, 0, stream>>>(pred, dsum, ybh);
  k_p2_mfma<<<dim3(NN / 64, BB), 256, 0, stream>>>(Mbuf, ybh, dsum, p2b);
  k_pred_head<<<BB * NN / 256, 256, 0, stream>>>(pred, p2b, maskb, w_cls1, b_cls1,
                                                 w_cls2, b_cls2, out, spnP);
  // --- feat branch (bf16 MFMA) ---
  k_gram2<<<dim3(2080, BB), 256, 0, stream>>>(spnP, ohbits, Mh, d2s);
  k_make_z<<<BB * DD * NN / 4 / 256, 256, 0, stream>>>(feat, d2s, zb);
  k_prep_w<<<DD * DD / 256, 256, 0, stream>>>(w_pro1, w_pro2, wb1, wb2);
  k_newfeat_mfma<<<dim3(64, 4, BB), 256, 0, stream>>>(Mh, zb, d2s, nfh);
  k_conv1_mfma<<<dim3(64, 4, BB), 256, 0, stream>>>(nfh, wb1, b_pro1, midh);
  k_conv2_mfma<<<dim3(64, 4, BB), 256, 0, stream>>>(midh, wb2, b_pro2,
                                                    out + (size_t)BB * CC * NN);
}

// Round 13
// 327.315 us; speedup vs baseline: 1.0183x; 1.0183x over previous
//
#include <hip/hip_runtime.h>

#define NN 4096   // H*W
#define DD 256    // feature channels
#define CC 19     // classes
#define BB 2      // batch

typedef __attribute__((ext_vector_type(8))) short bf16x8;     // bf16 MFMA A/B frag
typedef _Float16 f16x8 __attribute__((ext_vector_type(8)));   // fp16 MFMA A/B frag
typedef __attribute__((ext_vector_type(4))) float f32x4;      // MFMA C/D frag

#define GLL16(gp, lp) __builtin_amdgcn_global_load_lds( \
    (const __attribute__((address_space(1))) unsigned int*)(gp), \
    (__attribute__((address_space(3))) unsigned int*)(lp), 16, 0, 0)

__device__ inline unsigned short f2b(float f) {   // fp32 -> bf16 RNE
  unsigned int u = __float_as_uint(f);
  return (unsigned short)((u + 0x7FFFu + ((u >> 16) & 1u)) >> 16);
}
__device__ inline float b2f(unsigned short h) {
  return __uint_as_float(((unsigned int)h) << 16);
}
__device__ inline unsigned int pack2(float a, float b) {
  return (unsigned int)f2b(a) | ((unsigned int)f2b(b) << 16);
}
// fp32 -> (fp16 hi, fp16 lo*2^11): hi+2^-11*lo carries ~22 mantissa bits
__device__ inline void split16(float x, unsigned short& h, unsigned short& l) {
  _Float16 hh = (_Float16)x;
  float hf = (float)hh;
  _Float16 ll = (_Float16)((x - hf) * 2048.0f);
  h = *reinterpret_cast<unsigned short*>(&hh);
  l = *reinterpret_cast<unsigned short*>(&ll);
}

// ---------------------------------------------------------------------------
// K1 (merged mask_bits + norm_feat): softmax confidence mask + scrambled
// one-hot bitmasks + row-normalized split-fp16 features.
// ---------------------------------------------------------------------------
__global__ __launch_bounds__(256) void k_prep(const float* __restrict__ pred,
                                              const float* __restrict__ cw,
                                              const float* __restrict__ feat,
                                              float* __restrict__ maskb,
                                              unsigned int* __restrict__ ohbits,
                                              unsigned short* __restrict__ xh,
                                              unsigned short* __restrict__ xl) {
  int g = blockIdx.x * 256 + threadIdx.x;
  int b = g >> 12, n = g & (NN - 1);
  {
    const float* p = pred + (size_t)b * CC * NN + n;
    float v[CC];
    float mx = -1e30f; int am = 0;
#pragma unroll
    for (int c = 0; c < CC; ++c) {
      float t = p[(size_t)c * NN];
      v[c] = t;
      if (t > mx) { mx = t; am = c; }
    }
    float s = 0.f;
#pragma unroll
    for (int c = 0; c < CC; ++c) s += expf(v[c] - mx);
    float pprob = 1.f / s;
    float cmax = 0.f;
#pragma unroll
    for (int c = 0; c < CC; ++c) cmax = fmaxf(cmax, cw[c]);
    float cwm = cw[am] / (cmax + 1e-10f) * 0.95f;
    maskb[g] = (pprob >= 0.95f || pprob >= cwm) ? 1.f : 0.f;
    int h = n >> 6, w = n & 63;
    int L = w * (CC * 64) + am * 64 + h;     // flat index in [W,C,H]
    atomicOr(&ohbits[b * NN + L / CC], 1u << (L % CC));
  }
  {
    const float* f = feat + (size_t)b * DD * NN + n;
    float s = 0.f;
    for (int d = 0; d < DD; ++d) { float t = f[(size_t)d * NN]; s += t * t; }
    float r = 1.f / (sqrtf(s) + 1e-9f);
    size_t ob = ((size_t)b * NN + n) * DD;
    for (int d = 0; d < DD; d += 4) {
      ushort4 oh, ol;
      split16(f[(size_t)d * NN] * r, oh.x, ol.x);
      split16(f[(size_t)(d + 1) * NN] * r, oh.y, ol.y);
      split16(f[(size_t)(d + 2) * NN] * r, oh.z, ol.z);
      split16(f[(size_t)(d + 3) * NN] * r, oh.w, ol.w);
      *reinterpret_cast<ushort4*>(&xh[ob + d]) = oh;
      *reinterpret_cast<ushort4*>(&xl[ob + d]) = ol;
    }
  }
}

// ---------------------------------------------------------------------------
// K3: aff1 = clamp(Gram(xn), 0) via 3-pass split-fp16 MFMA (~fp32 accuracy).
// gll staging, linear LDS, both-sides slot swizzle, dbuf, one barrier per
// K-step.  fp32 output (R7 lesson).  XCD-chunked block swizzle (R12:
// FETCH -29%, verified).
// ---------------------------------------------------------------------------
__global__ __launch_bounds__(256, 2) void k_gram1(const unsigned short* __restrict__ xh,
                                                  const unsigned short* __restrict__ xl,
                                                  float* __restrict__ M) {
  int Lh = blockIdx.x;                 // hardware id 0..527 (round-robin XCDs)
  int L = (Lh & 7) * 66 + (Lh >> 3);   // bijective XCD-contiguous logical tile
  int b = blockIdx.y;
  int I = 0;
  while (L >= 32 - I) { L -= 32 - I; ++I; }
  int J = I + L;
  int i0 = I * 128, j0 = J * 128;
  float* Mb = M + (size_t)b * NN * NN;
  const unsigned short* XH = xh + (size_t)b * NN * DD;
  const unsigned short* XL = xl + (size_t)b * NN * DD;
  __shared__ unsigned short stage[2][4][128][32];   // 64 KB; reused as float buf
  int t = threadIdx.x;
  int wave = t >> 6, lane = t & 63;
  int wr = (wave & 1) * 64, wc = (wave >> 1) * 64;
  int lrow = lane & 15, quad = lane >> 4;
  int sel = (lrow >> 1) & 3;                        // read-side swizzle selector
  f32x4 accH[4][4] = {}, accL[4][4] = {};
  const unsigned short* src = (wave == 0) ? XH + (size_t)i0 * DD
                             : (wave == 1) ? XL + (size_t)i0 * DD
                             : (wave == 2) ? XH + (size_t)j0 * DD
                                           : XL + (size_t)j0 * DD;
  // per-lane staging address components (uniform across e and k0)
  int srow = lane >> 2;                              // row within 16-row group
  int spart = (lane & 3) ^ ((lane >> 3) & 3);        // pre-swizzled global part
  // prologue: stage chunk 0 into buffer 0
#pragma unroll
  for (int e = 0; e < 8; ++e)
    GLL16(&src[(size_t)(e * 16 + srow) * DD + spart * 8], &stage[0][wave][e * 16][0]);
  __syncthreads();
  int cur = 0;
  for (int k0 = 0; k0 < DD; k0 += 32) {
    if (k0 + 32 < DD) {   // async-stage next chunk; retires under the MFMA cluster
#pragma unroll
      for (int e = 0; e < 8; ++e)
        GLL16(&src[(size_t)(e * 16 + srow) * DD + k0 + 32 + spart * 8],
              &stage[cur ^ 1][wave][e * 16][0]);
    }
    f16x8 ah[4], al[4], bh[4], bl[4];
#pragma unroll
    for (int i = 0; i < 4; ++i) {
      int ra = wr + i * 16 + lrow;
      int rb = wc + i * 16 + lrow;
      int sl = (quad ^ sel) * 8;
      ah[i] = *reinterpret_cast<const f16x8*>(&stage[cur][0][ra][sl]);
      al[i] = *reinterpret_cast<const f16x8*>(&stage[cur][1][ra][sl]);
      bh[i] = *reinterpret_cast<const f16x8*>(&stage[cur][2][rb][sl]);
      bl[i] = *reinterpret_cast<const f16x8*>(&stage[cur][3][rb][sl]);
    }
#pragma unroll
    for (int i = 0; i < 4; ++i) {
#pragma unroll
      for (int j = 0; j < 4; ++j) {
        accH[i][j] = __builtin_amdgcn_mfma_f32_16x16x32_f16(ah[i], bh[j], accH[i][j], 0, 0, 0);
        accL[i][j] = __builtin_amdgcn_mfma_f32_16x16x32_f16(ah[i], bl[j], accL[i][j], 0, 0, 0);
        accL[i][j] = __builtin_amdgcn_mfma_f32_16x16x32_f16(al[i], bh[j], accL[i][j], 0, 0, 0);
      }
    }
    __syncthreads();   // drains vmcnt(0)+lgkmcnt(0): next buffer staged, reads done
    cur ^= 1;
  }
#pragma unroll
  for (int i = 0; i < 4; ++i)
#pragma unroll
    for (int j = 0; j < 4; ++j)
#pragma unroll
      for (int reg = 0; reg < 4; ++reg)
        accH[i][j][reg] = fmaxf(accH[i][j][reg] + accL[i][j][reg] * 4.8828125e-4f, 0.f);
  float* buf = (float*)stage;   // [64][132] floats = 33.8 KB <= 64 KB
  int rr = t >> 4, cc = t & 15;
  for (int half = 0; half < 2; ++half) {
    __syncthreads();
    if ((wr >> 6) == half) {
#pragma unroll
      for (int i = 0; i < 4; ++i)
#pragma unroll
        for (int j = 0; j < 4; ++j)
#pragma unroll
          for (int reg = 0; reg < 4; ++reg)
            buf[(i * 16 + quad * 4 + reg) * 132 + wc + j * 16 + lrow] = accH[i][j][reg];
    }
    __syncthreads();
#pragma unroll
    for (int i = 0; i < 4; ++i) {
      int row = rr + i * 16;
#pragma unroll
      for (int q = 0; q < 2; ++q) {
        int col = cc * 4 + q * 64;
        *reinterpret_cast<float4*>(&Mb[(size_t)(i0 + half * 64 + row) * NN + j0 + col]) =
            *reinterpret_cast<float4*>(&buf[row * 132 + col]);
      }
    }
  }
  if (I != J) {
    for (int half = 0; half < 2; ++half) {
      __syncthreads();
      if ((wc >> 6) == half) {
#pragma unroll
        for (int i = 0; i < 4; ++i)
#pragma unroll
          for (int j = 0; j < 4; ++j)
#pragma unroll
            for (int reg = 0; reg < 4; ++reg)
              buf[(j * 16 + lrow) * 132 + wr + i * 16 + quad * 4 + reg] = accH[i][j][reg];
      }
      __syncthreads();
#pragma unroll
      for (int i = 0; i < 4; ++i) {
        int row = rr + i * 16;
#pragma unroll
        for (int q = 0; q < 2; ++q) {
          int col = cc * 4 + q * 64;
          *reinterpret_cast<float4*>(&Mb[(size_t)(j0 + half * 64 + row) * NN + i0 + col]) =
              *reinterpret_cast<float4*>(&buf[row * 132 + col]);
        }
      }
    }
  }
}

// ---------------------------------------------------------------------------
// K4: per-row 21st-largest, ONE WAVE PER ROW, row in VGPRs.
// Pivot-prune select + sched_barrier fences (rule #18) + total
// self-verification with exact full-bisect fallback.
// ---------------------------------------------------------------------------
__global__ __launch_bounds__(256, 2) void k_topk(const float* __restrict__ M,
                                                 float* __restrict__ thr) {
  __shared__ unsigned int cbuf[4][64];
  int b = blockIdx.y;
  int wave = threadIdx.x >> 6, lane = threadIdx.x & 63;
  int n = blockIdx.x * 4 + wave;
  const float* row = M + (size_t)b * NN * NN + (size_t)n * NN;
  uint4 v[16];
#pragma unroll
  for (int e = 0; e < 16; ++e) {
    unsigned long long addr = (unsigned long long)(row + lane * 4 + e * 256);
    asm volatile("global_load_dwordx4 %0, %1, off" : "=v"(v[e]) : "v"(addr));
  }
  asm volatile("s_waitcnt vmcnt(0)" ::: "memory");
  __builtin_amdgcn_sched_barrier(0);   // rule #18: pin register-only consumers below the wait
  // ---- phase 1: per-lane max ----
  unsigned int mx = 0u;
#pragma unroll
  for (int e = 0; e < 16; ++e) {
    unsigned int a = v[e].x > v[e].y ? v[e].x : v[e].y;
    unsigned int c2 = v[e].z > v[e].w ? v[e].z : v[e].w;
    a = a > c2 ? a : c2;
    mx = mx > a ? mx : a;
  }
  // ---- phase 2: s = 21st-largest lane-max (1 value per lane) ----
  unsigned int lo = 0u, hi = 0x3FC00000u;   // values in [0, ~1.001]; 1.5f bound
  while (lo < hi) {
    unsigned int mid = lo + ((hi - lo + 1) >> 1);
    if (__popcll(__ballot(mx >= mid)) >= 21) lo = mid; else hi = mid - 1;
  }
  unsigned int s = lo;
  // ---- phase 3: compact values >= s into LDS ----
  unsigned int base = 0;
  unsigned long long ltmask = (1ull << lane) - 1ull;
#pragma unroll
  for (int e = 0; e < 16; ++e) {
#pragma unroll
    for (int q = 0; q < 4; ++q) {
      unsigned int val = (q == 0) ? v[e].x : (q == 1) ? v[e].y : (q == 2) ? v[e].z : v[e].w;
      unsigned long long mk = __ballot(val >= s);
      if (mk) {   // wave-uniform skip: most elements are below the pivot
        unsigned int pos = base + (unsigned int)__popcll(mk & ltmask);
        if (val >= s && pos < 64u) cbuf[wave][pos] = val;
        base += (unsigned int)__popcll(mk);
      }
    }
  }
  asm volatile("s_waitcnt lgkmcnt(0)" ::: "memory");
  __builtin_amdgcn_sched_barrier(0);
  unsigned int t = s;
  if (base <= 64u) {
    // ---- phase 4: exact bisect over <=64 compacted candidates ----
    unsigned int cand = (lane < (int)base) ? cbuf[wave][lane] : 0u;
    lo = s; hi = 0x3FC00000u;
    while (lo < hi) {
      unsigned int mid = lo + ((hi - lo + 1) >> 1);
      if (__popcll(__ballot(cand >= mid)) >= 21) lo = mid; else hi = mid - 1;
    }
    t = lo;
  }
  // ---- phase 5: total verification (t exact iff c1>=21 && c2<21) ----
  {
    unsigned int t1 = t + 1u;
    int c1 = 0, c2 = 0;
#pragma unroll
    for (int e = 0; e < 16; ++e) {
      c1 += (int)__popcll(__ballot(v[e].x >= t));
      c1 += (int)__popcll(__ballot(v[e].y >= t));
      c1 += (int)__popcll(__ballot(v[e].z >= t));
      c1 += (int)__popcll(__ballot(v[e].w >= t));
      c2 += (int)__popcll(__ballot(v[e].x >= t1));
      c2 += (int)__popcll(__ballot(v[e].y >= t1));
      c2 += (int)__popcll(__ballot(v[e].z >= t1));
      c2 += (int)__popcll(__ballot(v[e].w >= t1));
    }
    if (!(c1 >= 21 && c2 < 21)) {
      // exact fallback: original proven full-sweep bisection
      lo = 0u; hi = 0x40000000u;
      while (lo < hi) {
        unsigned int mid = lo + ((hi - lo + 1) >> 1);
        int c = 0;
#pragma unroll
        for (int e = 0; e < 16; ++e) {
          c += (int)__popcll(__ballot(v[e].x >= mid));
          c += (int)__popcll(__ballot(v[e].y >= mid));
          c += (int)__popcll(__ballot(v[e].z >= mid));
          c += (int)__popcll(__ballot(v[e].w >= mid));
        }
        if (c >= 21) lo = mid; else hi = mid - 1;
      }
      t = lo;
    }
  }
  if (lane == 0) thr[b * NN + n] = __uint_as_float(t);
}

// ---------------------------------------------------------------------------
// K5: sparsify + symmetrize.  aff1 is bit-exact symmetric, so
// As[i][j] = a*(1(a>=thr_i) + 1(a>=thr_j)) needs ONLY the (I,J) tile.
// Writes bf16 As packed into each tile's fp32 footprint + degree sums.
// ---------------------------------------------------------------------------
__global__ __launch_bounds__(256) void k_symm(float* __restrict__ M, const float* __restrict__ thr,
                                              float* __restrict__ dsum) {
  int L = blockIdx.x;          // 0..2079 triangular (64 tiles/dim)
  int b = blockIdx.y;
  int I = 0;
  while (L >= 64 - I) { L -= 64 - I; ++I; }
  int J = I + L;
  float* Mb = M + (size_t)b * NN * NN;
  unsigned short* Mus = (unsigned short*)Mb;
  const float* th = thr + b * NN;
  __shared__ float A[64][65];
  int t = threadIdx.x;
  int i0 = I * 64, j0 = J * 64;
  float areg[16];
#pragma unroll
  for (int e = 0; e < 16; ++e) {
    int lin = t + e * 256;
    int i = lin >> 6, j = lin & 63;
    areg[e] = Mb[(size_t)(i0 + i) * NN + j0 + j];
  }
#pragma unroll
  for (int e = 0; e < 16; ++e) {
    int lin = t + e * 256;
    int i = lin >> 6, j = lin & 63;
    float a = areg[e];
    float v = a * ((a >= th[i0 + i] ? 1.f : 0.f) + (a >= th[j0 + j] ? 1.f : 0.f));
    A[i][j] = v;
  }
  __syncthreads();
  {
    int i = t >> 2, seg = (t & 3) * 16;
    float v[16];
#pragma unroll
    for (int q = 0; q < 4; ++q)
      *reinterpret_cast<float4*>(&v[q * 4]) = *reinterpret_cast<float4*>(&A[i][seg + q * 4]);
    unsigned int pk[8];
#pragma unroll
    for (int q = 0; q < 8; ++q) pk[q] = pack2(v[2 * q], v[2 * q + 1]);
    size_t ub = 2 * (size_t)(i0 + i) * NN + 2 * (size_t)j0 + seg;
    *reinterpret_cast<int4*>(&Mus[ub])     = *reinterpret_cast<int4*>(&pk[0]);
    *reinterpret_cast<int4*>(&Mus[ub + 8]) = *reinterpret_cast<int4*>(&pk[4]);
  }
  if (I != J) {   // As is symmetric: mirror footprint gets A^T
    int j = t >> 2, seg = (t & 3) * 16;
    float v[16];
#pragma unroll
    for (int e = 0; e < 16; ++e) v[e] = A[seg + e][j];
    unsigned int pk[8];
#pragma unroll
    for (int q = 0; q < 8; ++q) pk[q] = pack2(v[2 * q], v[2 * q + 1]);
    size_t ub = 2 * (size_t)(j0 + j) * NN + 2 * (size_t)i0 + seg;
    *reinterpret_cast<int4*>(&Mus[ub])     = *reinterpret_cast<int4*>(&pk[0]);
    *reinterpret_cast<int4*>(&Mus[ub + 8]) = *reinterpret_cast<int4*>(&pk[4]);
  }
  if (t < 64) {
    float s = 0.f;
#pragma unroll
    for (int j = 0; j < 64; ++j) s += A[t][j];
    atomicAdd(&dsum[b * NN + i0 + t], s);
  } else if (t < 128 && I != J) {
    int j = t - 64;
    float s = 0.f;
#pragma unroll
    for (int i = 0; i < 64; ++i) s += A[i][j];
    atomicAdd(&dsum[b * NN + j0 + j], s);
  }
}

// ---------------------------------------------------------------------------
// K7: ybh[b][c][n] = bf16(d1[b][n] * pred[b][c][n]), zero-padded to 32 classes.
// d1 is the RAW degree sum; 1/sqrt(d+1e-10) inlined.
// ---------------------------------------------------------------------------
__global__ void k_make_yb(const float* __restrict__ pred, const float* __restrict__ d1,
                          unsigned short* __restrict__ ybh) {
  int g = blockIdx.x * 256 + threadIdx.x;   // BB*32*NN/4 threads
  int idx = g * 4;
  int b = idx / (32 * NN);
  int c = (idx / NN) & 31;
  int n = idx & (NN - 1);
  ushort4 o = make_ushort4(0, 0, 0, 0);
  if (c < CC) {
    float4 p = *reinterpret_cast<const float4*>(&pred[((size_t)b * CC + c) * NN + n]);
    const float* dd = d1 + b * NN + n;
    o.x = f2b(p.x * (1.f / sqrtf(dd[0] + 1e-10f)));
    o.y = f2b(p.y * (1.f / sqrtf(dd[1] + 1e-10f)));
    o.z = f2b(p.z * (1.f / sqrtf(dd[2] + 1e-10f)));
    o.w = f2b(p.w * (1.f / sqrtf(dd[3] + 1e-10f)));
  }
  *reinterpret_cast<ushort4*>(&ybh[idx]) = o;
}

// ---------------------------------------------------------------------------
// K8: p2 via MFMA.  GEMM: M=n (64-tile), N=c (32 padded), K=m (4096).
// gll staging, both-sides slot-XOR swizzle, dbuf, one barrier per K-step.
// d1 raw; rsqrt inlined in the epilogue.
// ---------------------------------------------------------------------------
__global__ __launch_bounds__(256, 2) void k_p2_mfma(
    const float* __restrict__ M, const unsigned short* __restrict__ ybh,
    const float* __restrict__ d1, float* __restrict__ p2b) {
  int b = blockIdx.y;
  int n0 = blockIdx.x * 64;
  const unsigned short* Mus = (const unsigned short*)(M + (size_t)b * NN * NN);
  const unsigned short* Y = ybh + (size_t)b * 32 * NN;
  __shared__ unsigned short As2[2][64][64];   // 16 KB
  __shared__ unsigned short Ys2[2][32][64];   // 8 KB
  int t = threadIdx.x;
  int wave = t >> 6, lane = t & 63;
  int wn = (wave & 1) * 32;
  int wc = (wave >> 1) * 16;
  int lrow = lane & 15, quad = lane >> 4;
  f32x4 acc[2] = {{0.f,0.f,0.f,0.f},{0.f,0.f,0.f,0.f}};
  // staging geometry: each GLL16 issue covers 8 rows x 128 B
  int lr3 = lane >> 3;                   // row within the 8-row group
  int srow = wave * 8 + lr3;             // + e*32 for As; direct for Ys
  int spart = (lane & 7) ^ lr3;          // pre-swizzled global 16B-part
  // prologue: stage K-chunk 0 into buffer 0
#pragma unroll
  for (int e = 0; e < 2; ++e)
    GLL16(&Mus[2 * (size_t)(n0 + e * 32 + srow) * NN + spart * 8],
          &As2[0][e * 32 + wave * 8][0]);
  GLL16(&Y[(size_t)srow * NN + spart * 8], &Ys2[0][wave * 8][0]);
  __syncthreads();
  int cur = 0;
  for (int m0 = 0; m0 < NN; m0 += 64) {
    if (m0 + 64 < NN) {   // async-stage next chunk; retires under the MFMA cluster
#pragma unroll
      for (int e = 0; e < 2; ++e)
        GLL16(&Mus[2 * (size_t)(n0 + e * 32 + srow) * NN + 2 * (size_t)(m0 + 64) + spart * 8],
              &As2[cur ^ 1][e * 32 + wave * 8][0]);
      GLL16(&Y[(size_t)srow * NN + m0 + 64 + spart * 8], &Ys2[cur ^ 1][wave * 8][0]);
    }
#pragma unroll
    for (int kc = 0; kc < 2; ++kc) {
      int sl = ((kc * 4 + quad) ^ (lrow & 7)) * 8;   // swizzled slot (shorts)
      bf16x8 bfr = *reinterpret_cast<const bf16x8*>(&Ys2[cur][wc + lrow][sl]);
#pragma unroll
      for (int i = 0; i < 2; ++i) {
        bf16x8 af = *reinterpret_cast<const bf16x8*>(&As2[cur][wn + i * 16 + lrow][sl]);
        acc[i] = __builtin_amdgcn_mfma_f32_16x16x32_bf16(af, bfr, acc[i], 0, 0, 0);
      }
    }
    __syncthreads();   // drains vmcnt(0)+lgkmcnt(0): next buffer staged, reads done
    cur ^= 1;
  }
  int c = wc + lrow;
  if (c < CC) {
#pragma unroll
    for (int i = 0; i < 2; ++i) {
#pragma unroll
      for (int reg = 0; reg < 4; ++reg) {
        int n = n0 + wn + i * 16 + quad * 4 + reg;
        float dv = 1.f / sqrtf(d1[b * NN + n] + 1e-10f);
        p2b[((size_t)b * NN + n) * CC + c] = dv * acc[i][reg];
      }
    }
  }
}

// ---------------------------------------------------------------------------
// K9: fused blend + 19x19 conv x2 -> pred_out, then softmax + cosine-normalize.
// Emits spnP[b][n][32] bf16 (zero-padded K) for the MFMA k_gram2.
// R26: 64-thread blocks x 128 (was 256x32 -- only 32 blocks left 87% of the
// GPU idle during ~700 FMA/thread).  Per-pixel math bit-identical.
// ---------------------------------------------------------------------------
__global__ __launch_bounds__(64) void k_pred_head(const float* __restrict__ pred,
    const float* __restrict__ p2b, const float* __restrict__ maskb,
    const float* __restrict__ w1, const float* __restrict__ b1,
    const float* __restrict__ w2, const float* __restrict__ b2,
    float* __restrict__ out, unsigned short* __restrict__ spnP) {
  __shared__ float sw1[CC * CC], sw2[CC * CC], sb1[CC], sb2[CC];
  int t = threadIdx.x;
  for (int i = t; i < CC * CC; i += 64) { sw1[i] = w1[i]; sw2[i] = w2[i]; }
  if (t < CC) { sb1[t] = b1[t]; sb2[t] = b2[t]; }
  __syncthreads();
  int g = blockIdx.x * 64 + t;
  int b = g >> 12, n = g & (NN - 1);
  float m = maskb[g];
  float ca = (m > 0.5f) ? 0.2f : 0.8f;
  float cb = (m > 0.5f) ? 0.8f : 0.2f;
  const float* P = pred + (size_t)b * CC * NN + n;
  const float* Q = p2b + (size_t)g * CC;
  float p3[CC];
#pragma unroll
  for (int c = 0; c < CC; ++c) p3[c] = ca * Q[c] + cb * P[(size_t)c * NN];
  float midv[CC];
#pragma unroll
  for (int o = 0; o < CC; ++o) {
    float s = sb1[o];
#pragma unroll
    for (int c = 0; c < CC; ++c) s += sw1[o * CC + c] * p3[c];
    midv[o] = s;
  }
  float ov[CC];
  float mx = -1e30f;
#pragma unroll
  for (int o = 0; o < CC; ++o) {
    float s = sb2[o];
#pragma unroll
    for (int c = 0; c < CC; ++c) s += sw2[o * CC + c] * midv[c];
    ov[o] = s;
    out[(size_t)b * CC * NN + (size_t)o * NN + n] = s;
    mx = fmaxf(mx, s);
  }
  float se = 0.f;
  float e[CC];
#pragma unroll
  for (int o = 0; o < CC; ++o) { e[o] = expf(ov[o] - mx); se += e[o]; }
  float inv = 1.f / se;
  float nrm = 0.f;
#pragma unroll
  for (int o = 0; o < CC; ++o) { float sp = e[o] * inv; e[o] = sp; nrm += sp * sp; }
  float rn = 1.f / (sqrtf(nrm) + 1e-9f);
  unsigned short sp[32];
#pragma unroll
  for (int o = 0; o < CC; ++o) sp[o] = f2b(e[o] * rn);
#pragma unroll
  for (int o = CC; o < 32; ++o) sp[o] = 0;
  unsigned short* dst = spnP + (size_t)g * 32;
#pragma unroll
  for (int q = 0; q < 4; ++q)
    *reinterpret_cast<int4*>(&dst[q * 8]) = *reinterpret_cast<int4*>(&sp[q * 8]);
}

// ---------------------------------------------------------------------------
// K10: aff_f = bitmask ? clamp(Gram(spn),0) : 0, writes bf16 + fused d2 sums.
// MFMA (16x16x32, K padded to 32); gll staging with the verified slot
// swizzle; epilogue via tr[64][66] ushort (conflict-free columns).
// Safe in bf16: NO selection operates downstream of aff_f.
// ---------------------------------------------------------------------------
__global__ __launch_bounds__(256) void k_gram2(const unsigned short* __restrict__ spnP,
    const unsigned int* __restrict__ bits, unsigned short* __restrict__ Mh,
    float* __restrict__ d2) {
  int L = blockIdx.x;          // 0..2079 triangular (64 tiles/dim)
  int b = blockIdx.y;
  int I = 0;
  while (L >= 64 - I) { L -= 64 - I; ++I; }
  int J = I + L;
  const unsigned short* X = spnP + (size_t)b * NN * 32;
  unsigned short* Mb = Mh + (size_t)b * NN * NN;
  __shared__ unsigned short As[64][32], Bs[64][32];   // 4 KB each
  __shared__ unsigned short tr[64][66];               // 8.25 KB
  __shared__ unsigned int bI[64], bJ[64];
  int t = threadIdx.x;
  int wave = t >> 6, lane = t & 63;
  int lrow = lane & 15, quad = lane >> 4;
  int i0 = I * 64, j0 = J * 64;
  // stage: each wave covers 16 rows (lane>>2) x 4 parts (lane&3), swizzled
  int srow = wave * 16 + (lane >> 2);
  int spart = (lane & 3) ^ ((lane >> 3) & 3);
  GLL16(&X[(size_t)(i0 + srow) * 32 + spart * 8], &As[wave * 16][0]);
  GLL16(&X[(size_t)(j0 + srow) * 32 + spart * 8], &Bs[wave * 16][0]);
  if (t < 64) bI[t] = bits[b * NN + i0 + t];
  else if (t < 128) bJ[t - 64] = bits[b * NN + j0 + t - 64];
  __syncthreads();
  int wi = wave & 1, wj = wave >> 1;
  int sl = (quad ^ ((lrow >> 1) & 3)) * 8;   // read-side swizzle (matches k_gram1)
  bf16x8 af[2], bfr[2];
#pragma unroll
  for (int i = 0; i < 2; ++i) {
    af[i]  = *reinterpret_cast<const bf16x8*>(&As[wi * 32 + i * 16 + lrow][sl]);
    bfr[i] = *reinterpret_cast<const bf16x8*>(&Bs[wj * 32 + i * 16 + lrow][sl]);
  }
  f32x4 acc[2][2] = {{{0.f,0.f,0.f,0.f},{0.f,0.f,0.f,0.f}},{{0.f,0.f,0.f,0.f},{0.f,0.f,0.f,0.f}}};
#pragma unroll
  for (int i = 0; i < 2; ++i)
#pragma unroll
    for (int j = 0; j < 2; ++j)
      acc[i][j] = __builtin_amdgcn_mfma_f32_16x16x32_bf16(af[i], bfr[j], acc[i][j], 0, 0, 0);
  // mask + clamp + round -> tr
#pragma unroll
  for (int i = 0; i < 2; ++i) {
#pragma unroll
    for (int j = 0; j < 2; ++j) {
#pragma unroll
      for (int reg = 0; reg < 4; ++reg) {
        int row = wi * 32 + i * 16 + quad * 4 + reg;
        int col = wj * 32 + j * 16 + lrow;
        bool keep = (bI[row] & bJ[col]) != 0u;
        float v = keep ? fmaxf(acc[i][j][reg], 0.f) : 0.f;
        tr[row][col] = f2b(v);
      }
    }
  }
  __syncthreads();
  // direct tile store (coalesced; 4B LDS reads, 2-way max aliasing)
  {
    int row = t >> 2, seg = (t & 3) * 16;
    unsigned int w[8];
#pragma unroll
    for (int k = 0; k < 8; ++k)
      w[k] = *reinterpret_cast<const unsigned int*>(&tr[row][seg + 2 * k]);
    *reinterpret_cast<int4*>(&Mb[(size_t)(i0 + row) * NN + j0 + seg])     =
        *reinterpret_cast<int4*>(&w[0]);
    *reinterpret_cast<int4*>(&Mb[(size_t)(i0 + row) * NN + j0 + seg + 8]) =
        *reinterpret_cast<int4*>(&w[4]);
  }
  if (I != J) {   // mirror transposed store (conflict-free column reads)
#pragma unroll
    for (int e = 0; e < 16; ++e) {
      int lin = t + e * 256;
      int jr = lin >> 6, ic = lin & 63;
      Mb[(size_t)(j0 + jr) * NN + i0 + ic] = tr[ic][jr];
    }
  }
  if (t < 64) {          // direct row sums
    float s = 0.f;
#pragma unroll
    for (int c = 0; c < 64; ++c) s += b2f(tr[t][c]);
    atomicAdd(&d2[b * NN + i0 + t], s);
  } else if (t < 128 && I != J) {   // mirror row sums (column of tr)
    int c = t - 64;
    float s = 0.f;
#pragma unroll
    for (int i = 0; i < 64; ++i) s += b2f(tr[i][c]);
    atomicAdd(&d2[b * NN + j0 + c], s);
  }
}

// ---------------------------------------------------------------------------
// K12a: zb[b][d][m] = bf16(feat[b][d][m] * d2[b][m]); d2 raw, rsqrt inline.
// R26: folds weight conversion (was k_prep_w) into blocks 0..63.
// ---------------------------------------------------------------------------
__global__ void k_make_z(const float* __restrict__ feat, const float* __restrict__ d2,
                         unsigned short* __restrict__ zb,
                         const float* __restrict__ w1, const float* __restrict__ w2,
                         unsigned short* __restrict__ wb1, unsigned short* __restrict__ wb2) {
  int g = blockIdx.x * 256 + threadIdx.x;   // BB*DD*NN/4 threads
  int idx = g * 4;
  int b = idx / (DD * NN);
  int m = idx & (NN - 1);
  float4 f = *reinterpret_cast<const float4*>(&feat[idx]);
  const float* dd = d2 + b * NN + m;
  ushort4 o;
  o.x = f2b(f.x * (1.f / sqrtf(dd[0] + 1e-10f)));
  o.y = f2b(f.y * (1.f / sqrtf(dd[1] + 1e-10f)));
  o.z = f2b(f.z * (1.f / sqrtf(dd[2] + 1e-10f)));
  o.w = f2b(f.w * (1.f / sqrtf(dd[3] + 1e-10f)));
  *reinterpret_cast<ushort4*>(&zb[idx]) = o;
  if (blockIdx.x < DD * DD / (4 * 256)) {   // 64 blocks: convert both weights
    int wi = idx;                            // 0 .. DD*DD-4, step 4
    float4 a = *reinterpret_cast<const float4*>(&w1[wi]);
    float4 c = *reinterpret_cast<const float4*>(&w2[wi]);
    ushort4 oa, oc;
    oa.x = f2b(a.x); oa.y = f2b(a.y); oa.z = f2b(a.z); oa.w = f2b(a.w);
    oc.x = f2b(c.x); oc.y = f2b(c.y); oc.z = f2b(c.z); oc.w = f2b(c.w);
    *reinterpret_cast<ushort4*>(&wb1[wi]) = oa;
    *reinterpret_cast<ushort4*>(&wb2[wi]) = oc;
  }
}

// ---------------------------------------------------------------------------
// K13: new_feat via MFMA.  GEMM: M=d(64), N=n(64), K=4096.
// Single kernel accumulates full K, epilogue applies rsqrt(d2) and stores
// bf16 nfh directly.  gll/dbuf/swizzle K-step structure.
// ---------------------------------------------------------------------------
__global__ __launch_bounds__(256, 2) void k_newfeat_mfma(
    const unsigned short* __restrict__ Mh, const unsigned short* __restrict__ zb,
    const float* __restrict__ d2, unsigned short* __restrict__ nfh) {
  int b = blockIdx.z;
  int nblk = blockIdx.x;   // 64
  int dblk = blockIdx.y;   // 4
  const unsigned short* A = zb + (size_t)b * DD * NN + (size_t)(dblk * 64) * NN;
  const unsigned short* Bm = Mh + (size_t)b * NN * NN + (size_t)(nblk * 64) * NN;
  __shared__ unsigned short As[2][64][64];   // 16 KB
  __shared__ unsigned short Bs[2][64][64];   // 16 KB
  int t = threadIdx.x;
  int wave = t >> 6, lane = t & 63;
  int wd = (wave & 1) * 32, wn = (wave >> 1) * 32;
  int lrow = lane & 15, quad = lane >> 4;
  f32x4 acc[2][2] = {{{0.f,0.f,0.f,0.f},{0.f,0.f,0.f,0.f}},{{0.f,0.f,0.f,0.f},{0.f,0.f,0.f,0.f}}};
  // staging geometry: per wave, issue e covers rows e*32 + wave*8 .. +8
  int lr3 = lane >> 3;                   // 0..7: row within the wave's 8-row group
  int srow = wave * 8 + lr3;             // + e*32 = global tile row
  int spart = (lane & 7) ^ lr3;          // pre-swizzled global 16B-part
  // prologue: stage K-chunk 0 into buffer 0
#pragma unroll
  for (int e = 0; e < 2; ++e) {
    GLL16(&A [(size_t)(e * 32 + srow) * NN + spart * 8], &As[0][e * 32 + wave * 8][0]);
    GLL16(&Bm[(size_t)(e * 32 + srow) * NN + spart * 8], &Bs[0][e * 32 + wave * 8][0]);
  }
  __syncthreads();
  int cur = 0;
  for (int m0 = 0; m0 < NN; m0 += 64) {
    if (m0 + 64 < NN) {   // async-stage next chunk; retires under the MFMA cluster
#pragma unroll
      for (int e = 0; e < 2; ++e) {
        GLL16(&A [(size_t)(e * 32 + srow) * NN + m0 + 64 + spart * 8],
              &As[cur ^ 1][e * 32 + wave * 8][0]);
        GLL16(&Bm[(size_t)(e * 32 + srow) * NN + m0 + 64 + spart * 8],
              &Bs[cur ^ 1][e * 32 + wave * 8][0]);
      }
    }
#pragma unroll
    for (int kc = 0; kc < 2; ++kc) {
      int sl = ((kc * 4 + quad) ^ (lrow & 7)) * 8;   // swizzled slot (shorts)
      bf16x8 af[2], bfr[2];
#pragma unroll
      for (int i = 0; i < 2; ++i) {
        af[i]  = *reinterpret_cast<const bf16x8*>(&As[cur][wd + i * 16 + lrow][sl]);
        bfr[i] = *reinterpret_cast<const bf16x8*>(&Bs[cur][wn + i * 16 + lrow][sl]);
      }
#pragma unroll
      for (int i = 0; i < 2; ++i)
#pragma unroll
        for (int j = 0; j < 2; ++j)
          acc[i][j] = __builtin_amdgcn_mfma_f32_16x16x32_bf16(af[i], bfr[j], acc[i][j], 0, 0, 0);
    }
    __syncthreads();   // drains vmcnt(0)+lgkmcnt(0): next buffer staged, reads done
    cur ^= 1;
  }
#pragma unroll
  for (int j = 0; j < 2; ++j) {
    int n = nblk * 64 + wn + j * 16 + lrow;
    float sc = 1.f / sqrtf(d2[b * NN + n] + 1e-10f);
#pragma unroll
    for (int i = 0; i < 2; ++i) {
      int d = dblk * 64 + wd + i * 16 + quad * 4;
      ushort4 o;
      o.x = f2b(acc[i][j].x * sc); o.y = f2b(acc[i][j].y * sc);
      o.z = f2b(acc[i][j].z * sc); o.w = f2b(acc[i][j].w * sc);
      *reinterpret_cast<ushort4*>(&nfh[((size_t)b * NN + n) * DD + d]) = o;
    }
  }
}

// ---------------------------------------------------------------------------
// K14: conv1 via MFMA. GEMM: M=n, N=o1, K=d.
// ---------------------------------------------------------------------------
__global__ __launch_bounds__(256) void k_conv1_mfma(
    const unsigned short* __restrict__ nfh, const unsigned short* __restrict__ wb1,
    const float* __restrict__ b1, unsigned short* __restrict__ midh) {
  int b = blockIdx.z;
  int nblk = blockIdx.x;   // 64
  int oblk = blockIdx.y;   // 4
  int n0 = nblk * 64, o0 = oblk * 64;
  __shared__ unsigned short As[64][72];
  __shared__ unsigned short Bs[64][72];
  int t = threadIdx.x;
  int wave = t >> 6, lane = t & 63;
  int wn = (wave & 1) * 32, wo = (wave >> 1) * 32;
  int lrow = lane & 15, quad = lane >> 4;
  f32x4 acc[2][2] = {{{0.f,0.f,0.f,0.f},{0.f,0.f,0.f,0.f}},{{0.f,0.f,0.f,0.f},{0.f,0.f,0.f,0.f}}};
  int sr = t >> 3, sc = (t & 7) * 8;
  for (int d0 = 0; d0 < DD; d0 += 64) {
#pragma unroll
    for (int e = 0; e < 2; ++e) {
      int rr = sr + e * 32;
      *reinterpret_cast<int4*>(&As[rr][sc]) =
          *reinterpret_cast<const int4*>(&nfh[((size_t)b * NN + n0 + rr) * DD + d0 + sc]);
      *reinterpret_cast<int4*>(&Bs[rr][sc]) =
          *reinterpret_cast<const int4*>(&wb1[(size_t)(o0 + rr) * DD + d0 + sc]);
    }
    __syncthreads();
#pragma unroll
    for (int kc = 0; kc < 2; ++kc) {
      int ko = kc * 32 + quad * 8;
      bf16x8 af[2], bfr[2];
#pragma unroll
      for (int i = 0; i < 2; ++i) {
        af[i]  = *reinterpret_cast<const bf16x8*>(&As[wn + i * 16 + lrow][ko]);
        bfr[i] = *reinterpret_cast<const bf16x8*>(&Bs[wo + i * 16 + lrow][ko]);
      }
#pragma unroll
      for (int i = 0; i < 2; ++i)
#pragma unroll
        for (int j = 0; j < 2; ++j)
          acc[i][j] = __builtin_amdgcn_mfma_f32_16x16x32_bf16(af[i], bfr[j], acc[i][j], 0, 0, 0);
    }
    __syncthreads();
  }
#pragma unroll
  for (int j = 0; j < 2; ++j) {
    int o = o0 + wo + j * 16 + lrow;
    float bias = b1[o];
#pragma unroll
    for (int i = 0; i < 2; ++i) {
      int nb = n0 + wn + i * 16 + quad * 4;
      ushort4 v;
      v.x = f2b(fmaxf(acc[i][j].x + bias, 0.f));
      v.y = f2b(fmaxf(acc[i][j].y + bias, 0.f));
      v.z = f2b(fmaxf(acc[i][j].z + bias, 0.f));
      v.w = f2b(fmaxf(acc[i][j].w + bias, 0.f));
      *reinterpret_cast<ushort4*>(&midh[((size_t)b * DD + o) * NN + nb]) = v;
    }
  }
}

// ---------------------------------------------------------------------------
// K15: conv2 via MFMA. GEMM: M=n, N=o2, K=o1.
// ---------------------------------------------------------------------------
__global__ __launch_bounds__(256) void k_conv2_mfma(
    const unsigned short* __restrict__ midh, const unsigned short* __restrict__ wb2,
    const float* __restrict__ b2, float* __restrict__ outp) {
  int b = blockIdx.z;
  int nblk = blockIdx.x;   // 64
  int oblk = blockIdx.y;   // 4
  int n0 = nblk * 64, o0 = oblk * 64;
  __shared__ unsigned short As[64][72];
  __shared__ unsigned short Bs[64][72];
  int t = threadIdx.x;
  int wave = t >> 6, lane = t & 63;
  int wn = (wave & 1) * 32, wo = (wave >> 1) * 32;
  int lrow = lane & 15, quad = lane >> 4;
  f32x4 acc[2][2] = {{{0.f,0.f,0.f,0.f},{0.f,0.f,0.f,0.f}},{{0.f,0.f,0.f,0.f},{0.f,0.f,0.f,0.f}}};
  int sr = t >> 3, sc = (t & 7) * 8;
  for (int d0 = 0; d0 < DD; d0 += 64) {
#pragma unroll
    for (int e = 0; e < 2; ++e) {
      int rr = sr + e * 32;
      *reinterpret_cast<int4*>(&Bs[rr][sc]) =
          *reinterpret_cast<const int4*>(&wb2[(size_t)(o0 + rr) * DD + d0 + sc]);
      unsigned short v[8];
      *reinterpret_cast<int4*>(v) =
          *reinterpret_cast<const int4*>(&midh[((size_t)b * DD + d0 + rr) * NN + n0 + sc]);
#pragma unroll
      for (int j = 0; j < 8; ++j) As[sc + j][rr] = v[j];
    }
    __syncthreads();
#pragma unroll
    for (int kc = 0; kc < 2; ++kc) {
      int ko = kc * 32 + quad * 8;
      bf16x8 af[2], bfr[2];
#pragma unroll
      for (int i = 0; i < 2; ++i) {
        af[i]  = *reinterpret_cast<const bf16x8*>(&As[wn + i * 16 + lrow][ko]);
        bfr[i] = *reinterpret_cast<const bf16x8*>(&Bs[wo + i * 16 + lrow][ko]);
      }
#pragma unroll
      for (int i = 0; i < 2; ++i)
#pragma unroll
        for (int j = 0; j < 2; ++j)
          acc[i][j] = __builtin_amdgcn_mfma_f32_16x16x32_bf16(af[i], bfr[j], acc[i][j], 0, 0, 0);
    }
    __syncthreads();
  }
#pragma unroll
  for (int j = 0; j < 2; ++j) {
    int o = o0 + wo + j * 16 + lrow;
    float bias = b2[o];
#pragma unroll
    for (int i = 0; i < 2; ++i) {
      int nb = n0 + wn + i * 16 + quad * 4;
      float4 v = make_float4(acc[i][j].x + bias, acc[i][j].y + bias,
                             acc[i][j].z + bias, acc[i][j].w + bias);
      *reinterpret_cast<float4*>(&outp[((size_t)b * DD + o) * NN + nb]) = v;
    }
  }
}

// ---------------------------------------------------------------------------
extern "C" void kernel_launch(void* const* d_in, const int* in_sizes, int n_in,
                              void* d_out, int out_size, void* d_ws, size_t ws_size,
                              hipStream_t stream) {
  (void)in_sizes; (void)n_in; (void)out_size; (void)ws_size;
  const float* pred   = (const float*)d_in[0];
  const float* feat   = (const float*)d_in[1];
  const float* w_cls1 = (const float*)d_in[2];
  const float* b_cls1 = (const float*)d_in[3];
  const float* w_cls2 = (const float*)d_in[4];
  const float* b_cls2 = (const float*)d_in[5];
  const float* w_pro1 = (const float*)d_in[6];
  const float* b_pro1 = (const float*)d_in[7];
  const float* w_pro2 = (const float*)d_in[8];
  const float* b_pro2 = (const float*)d_in[9];
  const float* cw     = (const float*)d_in[10];
  float* out = (float*)d_out;

  // workspace layout (R26: dsum/d2s/ohbits contiguous -> single memset)
  float* Mbuf = (float*)d_ws;                               // B*N*N fp32 (aff1 / packed-bf16 As / bf16 aff_f)
  float* spnT = Mbuf + (size_t)BB * NN * NN;                 // region reused: spnP bf16 [B][N][32]
  float* p2b  = spnT + (size_t)BB * CC * NN;
  float* thr  = p2b + (size_t)BB * NN * CC;
  float* dsum = thr + BB * NN;                               // raw d1 sums
  float* d2s  = dsum + BB * NN;                              // raw d2 sums
  unsigned int* ohbits = (unsigned int*)(d2s + BB * NN);     // contiguous with d2s
  float* maskb = (float*)(ohbits + BB * NN);
  unsigned short* xh   = (unsigned short*)(maskb + BB * NN);   // B*N*D fp16 hi
  unsigned short* xl   = xh + (size_t)BB * NN * DD;            // B*N*D fp16 lo*2^11
  unsigned short* nfh  = xl + (size_t)BB * NN * DD;            // B*N*D bf16
  unsigned short* midh = nfh + (size_t)BB * NN * DD;           // B*D*N bf16
  unsigned short* zb   = midh + (size_t)BB * DD * NN;          // B*D*N bf16
  unsigned short* wb1  = zb + (size_t)BB * DD * NN;            // D*D bf16
  unsigned short* wb2  = wb1 + (size_t)DD * DD;                // D*D bf16
  unsigned short* ybh  = wb2 + (size_t)DD * DD;                // B*32*N bf16 (padded y)
  unsigned short* Mh   = (unsigned short*)Mbuf;
  unsigned short* spnP = (unsigned short*)spnT;                // bf16 [B][N][32]

  hipMemsetAsync(dsum, 0, sizeof(float) * 3 * BB * NN, stream);   // dsum + d2s + ohbits

  // --- pred branch ---
  k_prep<<<BB * NN / 256, 256, 0, stream>>>(pred, cw, feat, maskb, ohbits, xh, xl);
  k_gram1<<<dim3(528, BB), 256, 0, stream>>>(xh, xl, Mbuf);
  k_topk<<<dim3(NN / 4, BB), 256, 0, stream>>>(Mbuf, thr);
  k_symm<<<dim3(2080, BB), 256, 0, stream>>>(Mbuf, thr, dsum);
  k_make_yb<<<BB * 32 * NN / 4 / 256, 256, 0, stream>>>(pred, dsum, ybh);
  k_p2_mfma<<<dim3(NN / 64, BB), 256, 0, stream>>>(Mbuf, ybh, dsum, p2b);
  k_pred_head<<<BB * NN / 64, 64, 0, stream>>>(pred, p2b, maskb, w_cls1, b_cls1,
                                               w_cls2, b_cls2, out, spnP);
  // --- feat branch (bf16 MFMA) ---
  k_gram2<<<dim3(2080, BB), 256, 0, stream>>>(spnP, ohbits, Mh, d2s);
  k_make_z<<<BB * DD * NN / 4 / 256, 256, 0, stream>>>(feat, d2s, zb,
                                                       w_pro1, w_pro2, wb1, wb2);
  k_newfeat_mfma<<<dim3(64, 4, BB), 256, 0, stream>>>(Mh, zb, d2s, nfh);
  k_conv1_mfma<<<dim3(64, 4, BB), 256, 0, stream>>>(nfh, wb1, b_pro1, midh);
  k_conv2_mfma<<<dim3(64, 4, BB), 256, 0, stream>>>(midh, wb2, b_pro2,
                                                    out + (size_t)BB * CC * NN);
}